// Round 2
// baseline (1999.666 us; speedup 1.0000x reference)
//
#include <hip/hip_runtime.h>
#include <hip/hip_fp16.h>
#include <math.h>

// ---------------- problem constants ----------------
constexpr int H   = 256;
constexpr int ID  = 512;   // image_dim == text_dim
constexpr int NC  = 80;
constexpr int BT  = 131072;

constexpr int MROWS = 32;              // rows per block (2 row-tiles of 16)
constexpr int NBLK  = BT / MROWS;      // 4096, exact -> no tail predication

typedef _Float16 half8  __attribute__((ext_vector_type(8)));
typedef float    floatx4 __attribute__((ext_vector_type(4)));

#define MFMA16(a,b,c) __builtin_amdgcn_mfma_f32_16x16x32_f16((a),(b),(c),0,0,0)

__device__ inline half8 splat8(_Float16 v){ half8 r = {v,v,v,v,v,v,v,v}; return r; }

// ---------------- device-global fp16 weights (transposed [N][K]) ----------------
__device__ __align__(16) _Float16 g_WieT[H*ID];     // [256][512]
__device__ __align__(16) _Float16 g_WteT[H*ID];     // [256][512]
__device__ __align__(16) _Float16 g_WvT [H*H];      // [256][256]
__device__ __align__(16) _Float16 g_WipT[2*H*H];    // [512][256]
__device__ __align__(16) _Float16 g_WtpT[2*H*H];    // [512][256]
__device__ __align__(16) _Float16 g_WofT[2*H*H];    // [512][256]  = (Wo@W_fp)^T
__device__ __align__(16) _Float16 g_Wc1T[H*2*H];    // [256][512]
__device__ __align__(16) _Float16 g_Wc2T[NC*H];     // [80][256]
__device__ __align__(16) float g_wkeff[4*H];        // [4][256]  Wk folded with q, /8 (h-major)
__device__ float g_sbias[4];                        // bk folded with q, /8
__device__ float g_biasof[2*H];                     // bo@W_fp + b_fp

// ---------------- LDS layout (dynamic) ----------------
// half-unit offsets:
//   encI  [32][264] @ 0       (bytes [0,16896))      -> later low part of fused -> h1
//   encT  [32][264] @ 8448    (bytes [16896,33792))  -> later pool -> high part of fused
//   fused [32][520] overlays both (bytes [0,33280))
constexpr int OFF_EI = 0;
constexpr int OFF_ET = 8448;      // half units
// byte offsets for f32 scalar regions:
constexpr int OFF_SUMI = 33792;   // f32[32][4]
constexpr int OFF_SUMT = 34304;   // f32[32][4]
constexpr int OFF_ATT  = 34816;   // f32[32][4][2]
constexpr int OFF_SELB = 35840;   // f32[32]
constexpr int OFF_SELI = 35968;
constexpr int OFF_SELT = 36096;
constexpr int SMEM_BYTES = 36224; // 36.2KB -> 4 blocks/CU (144896 <= 163840)

// ============================ setup kernel ============================
// blocks: [0,512) WieT | [512,1024) WteT | [1024,1280) WvT | [1280,1792) WipT
// [1792,2304) WtpT | [2304,2816) Wc1T | [2816,2896) Wc2T | [2896,3408) WofT
// [3408] wkeff+sbias | [3409,3411) biasof
__global__ void aecf_setup(const float* __restrict__ W_ie, const float* __restrict__ W_te,
                           const float* __restrict__ fq,   const float* __restrict__ Wq,
                           const float* __restrict__ bq,   const float* __restrict__ Wk,
                           const float* __restrict__ bk,   const float* __restrict__ Wv,
                           const float* __restrict__ Wo,   const float* __restrict__ bo,
                           const float* __restrict__ W_ip, const float* __restrict__ W_tp,
                           const float* __restrict__ W_fp, const float* __restrict__ b_fp,
                           const float* __restrict__ Wc1,  const float* __restrict__ Wc2)
{
    __shared__ float qv[256];
    int b = blockIdx.x, t = threadIdx.x;

    if (b < 512) { int e = b*256+t; int k=e>>8, n=e&255; g_WieT[n*512+k] = (_Float16)W_ie[e]; return; }
    b -= 512;
    if (b < 512) { int e = b*256+t; int k=e>>8, n=e&255; g_WteT[n*512+k] = (_Float16)W_te[e]; return; }
    b -= 512;
    if (b < 256) { int e = b*256+t; int k=e>>8, n=e&255; g_WvT[n*256+k] = (_Float16)Wv[e]; return; }
    b -= 256;
    if (b < 512) { int e = b*256+t; int k=e>>9, n=e&511; g_WipT[n*256+k] = (_Float16)W_ip[e]; return; }
    b -= 512;
    if (b < 512) { int e = b*256+t; int k=e>>9, n=e&511; g_WtpT[n*256+k] = (_Float16)W_tp[e]; return; }
    b -= 512;
    if (b < 512) { int e = b*256+t; int k=e>>8, n=e&255; g_Wc1T[n*512+k] = (_Float16)Wc1[e]; return; }
    b -= 512;
    if (b < 80)  { int e = b*256+t; int k=e/80, n=e%80;  g_Wc2T[n*256+k] = (_Float16)Wc2[e]; return; }
    b -= 80;
    if (b < 512) {               // WofT row n = b : (Wo @ W_fp)^T
        int n = b, c = t;
        float s = 0.f;
        for (int m = 0; m < 256; m++) s += Wo[c*256+m] * W_fp[m*512+n];
        g_WofT[n*256+c] = (_Float16)s;
        return;
    }
    b -= 512;
    if (b == 0) {                // q = fq@Wq+bq ; wk_eff ; sbias
        float a = bq[t];
        for (int i = 0; i < 256; i++) a += fq[i] * Wq[i*256+t];
        qv[t] = a;
        __syncthreads();
        for (int h = 0; h < 4; h++) {
            float s = 0.f;
            for (int d = 0; d < 64; d++) s += Wk[t*256 + h*64+d] * qv[h*64+d];
            g_wkeff[h*256 + t] = s * 0.125f;           // [h][c] layout for vector loads
        }
        if (t < 4) {
            float s = 0.f;
            for (int d = 0; d < 64; d++) s += bk[t*64+d] * qv[t*64+d];
            g_sbias[t] = s * 0.125f;
        }
        return;
    }
    b -= 1;
    {                            // biasof = bo@W_fp + b_fp
        int n = b*256 + t;
        float s = b_fp[n];
        for (int m = 0; m < 256; m++) s += bo[m] * W_fp[m*512+n];
        g_biasof[n] = s;
    }
}

// ============================ main fused kernel ============================
__global__ __launch_bounds__(256, 4)
void aecf_main(const float* __restrict__ img, const float* __restrict__ txt,
               const float* __restrict__ b_ie, const float* __restrict__ b_te,
               const float* __restrict__ bv,   const float* __restrict__ b_ip,
               const float* __restrict__ b_tp, const float* __restrict__ bc1,
               const float* __restrict__ bc2,  float* __restrict__ out)
{
    extern __shared__ char smem[];
    _Float16* encI  = (_Float16*)smem + OFF_EI;   // [32][264]
    _Float16* encT  = (_Float16*)smem + OFF_ET;   // [32][264]
    _Float16* pool  = (_Float16*)smem + OFF_ET;   // [32][264], overlays encT after B3
    _Float16* fused = (_Float16*)smem;            // [32][520] overlays encI+encT
    _Float16* h1    = (_Float16*)smem;            // [32][264] overlays fused low after B6a
    float* sumI = (float*)(smem + OFF_SUMI);
    float* sumT = (float*)(smem + OFF_SUMT);
    float* attn = (float*)(smem + OFF_ATT);
    float* selb = (float*)(smem + OFF_SELB);
    float* seli = (float*)(smem + OFF_SELI);
    float* selt = (float*)(smem + OFF_SELT);

    const int tid  = threadIdx.x;
    const int w    = tid >> 6;      // wave 0..3
    const int lane = tid & 63;
    const int l16  = lane & 15;
    const int q4   = lane >> 4;
    const int base = blockIdx.x * MROWS;

    // ---------------- stage 1: encoders, register-double-buffered input prefetch ----------------
    auto encode = [&](const float* __restrict__ src, const _Float16* __restrict__ WT,
                      const float* __restrict__ bias, _Float16* dstE, float* sumLds) {
        floatx4 acc[2][4];
        #pragma unroll
        for (int rt = 0; rt < 2; rt++)
            #pragma unroll
            for (int ct = 0; ct < 4; ct++) acc[rt][ct] = (floatx4){0.f,0.f,0.f,0.f};
        float sab[2] = {0.f, 0.f};

        const float* p0 = src + (size_t)(base + l16)*ID + q4*8;
        const float* p1 = src + (size_t)(base + 16 + l16)*ID + q4*8;
        // prefetch ks=0
        floatx4 n00 = *(const floatx4*)p0, n01 = *(const floatx4*)(p0+4);
        floatx4 n10 = *(const floatx4*)p1, n11 = *(const floatx4*)(p1+4);

        for (int ks = 0; ks < 16; ks++) {
            const int k0 = ks*32 + q4*8;
            // convert current fragments
            half8 afr[2];
            {
                half8 a;
                a[0]=(_Float16)n00[0]; a[1]=(_Float16)n00[1]; a[2]=(_Float16)n00[2]; a[3]=(_Float16)n00[3];
                a[4]=(_Float16)n01[0]; a[5]=(_Float16)n01[1]; a[6]=(_Float16)n01[2]; a[7]=(_Float16)n01[3];
                afr[0] = a;
                half8 c;
                c[0]=(_Float16)n10[0]; c[1]=(_Float16)n10[1]; c[2]=(_Float16)n10[2]; c[3]=(_Float16)n10[3];
                c[4]=(_Float16)n11[0]; c[5]=(_Float16)n11[1]; c[6]=(_Float16)n11[2]; c[7]=(_Float16)n11[3];
                afr[1] = c;
            }
            if (w == 0) {  // presence detection partials (before nx overwritten)
                sab[0] += fabsf(n00[0])+fabsf(n00[1])+fabsf(n00[2])+fabsf(n00[3])
                        + fabsf(n01[0])+fabsf(n01[1])+fabsf(n01[2])+fabsf(n01[3]);
                sab[1] += fabsf(n10[0])+fabsf(n10[1])+fabsf(n10[2])+fabsf(n10[3])
                        + fabsf(n11[0])+fabsf(n11[1])+fabsf(n11[2])+fabsf(n11[3]);
            }
            // prefetch ks+1 (HBM latency hides under the weight loads + MFMAs below)
            if (ks < 15) {
                const int kn = (ks+1)*32;
                n00 = *(const floatx4*)(p0 + kn);  n01 = *(const floatx4*)(p0 + kn + 4);
                n10 = *(const floatx4*)(p1 + kn);  n11 = *(const floatx4*)(p1 + kn + 4);
            }
            #pragma unroll
            for (int ct = 0; ct < 4; ct++) {
                const int ng = w*64 + ct*16 + l16;
                half8 bfr = *(const half8*)(WT + (size_t)ng*512 + k0);
                #pragma unroll
                for (int rt = 0; rt < 2; rt++) acc[rt][ct] = MFMA16(afr[rt], bfr, acc[rt][ct]);
            }
        }
        #pragma unroll
        for (int ct = 0; ct < 4; ct++) {
            const int colg = w*64 + ct*16 + l16;
            const float bb = bias[colg];
            #pragma unroll
            for (int rt = 0; rt < 2; rt++)
                #pragma unroll
                for (int r = 0; r < 4; r++) {
                    float v = acc[rt][ct][r] + bb;
                    v = v > 0.f ? v : 0.f;                     // relu
                    dstE[(rt*16 + q4*4 + r)*264 + colg] = (_Float16)v;
                }
        }
        if (w == 0) {
            #pragma unroll
            for (int rt = 0; rt < 2; rt++) sumLds[(rt*16 + l16)*4 + q4] = sab[rt];
        }
    };
    encode(img, g_WieT, b_ie, encI, sumI);
    encode(txt, g_WteT, b_te, encT, sumT);
    __syncthreads();   // B1

    // ---------------- stage 2: flags + scores + softmax (vectorized) ----------------
    if (tid < 128) {
        const int row = tid >> 2, h = tid & 3;
        float sI = sumI[row*4]+sumI[row*4+1]+sumI[row*4+2]+sumI[row*4+3];
        float sT = sumT[row*4]+sumT[row*4+1]+sumT[row*4+2]+sumT[row*4+3];
        bool pi = sI > 0.f, pt = sT > 0.f;
        if (h == 0) {
            selb[row] = (pi && pt)  ? 1.f : 0.f;
            seli[row] = (pi && !pt) ? 1.f : 0.f;
            selt[row] = (!pi && pt) ? 1.f : 0.f;
        }
        float s0 = g_sbias[h], s1 = s0;
        const _Float16* rI = encI + row*264;
        const _Float16* rT = encT + row*264;
        const float* wkh = g_wkeff + h*256;
        for (int c8 = 0; c8 < 256; c8 += 8) {
            half8 eI = *(const half8*)(rI + c8);
            half8 eT = *(const half8*)(rT + c8);
            floatx4 wa = *(const floatx4*)(wkh + c8);
            floatx4 wb = *(const floatx4*)(wkh + c8 + 4);
            s0 += wa[0]*(float)eI[0] + wa[1]*(float)eI[1] + wa[2]*(float)eI[2] + wa[3]*(float)eI[3]
                + wb[0]*(float)eI[4] + wb[1]*(float)eI[5] + wb[2]*(float)eI[6] + wb[3]*(float)eI[7];
            s1 += wa[0]*(float)eT[0] + wa[1]*(float)eT[1] + wa[2]*(float)eT[2] + wa[3]*(float)eT[3]
                + wb[0]*(float)eT[4] + wb[1]*(float)eT[5] + wb[2]*(float)eT[6] + wb[3]*(float)eT[7];
        }
        const float a0 = 1.f / (1.f + __expf(s1 - s0));
        attn[(row*4+h)*2]   = a0;
        attn[(row*4+h)*2+1] = 1.f - a0;
    }
    __syncthreads();   // B2

    // ---------------- stage 3: img/txt projections into pacc ----------------
    floatx4 pacc[2][8];
    #pragma unroll
    for (int rt = 0; rt < 2; rt++)
        #pragma unroll
        for (int ct = 0; ct < 8; ct++) pacc[rt][ct] = (floatx4){0.f,0.f,0.f,0.f};

    {   // img_out contribution: (seli * encI) @ W_ip
        _Float16 s[2];
        #pragma unroll
        for (int rt = 0; rt < 2; rt++) s[rt] = (_Float16)seli[rt*16 + l16];
        for (int ks = 0; ks < 8; ks++) {
            const int k0 = ks*32 + q4*8;
            half8 afr[2];
            #pragma unroll
            for (int rt = 0; rt < 2; rt++)
                afr[rt] = (*(const half8*)(encI + (rt*16+l16)*264 + k0)) * splat8(s[rt]);
            #pragma unroll
            for (int ct = 0; ct < 8; ct++) {
                const int ng = w*128 + ct*16 + l16;
                half8 bfr = *(const half8*)(g_WipT + (size_t)ng*256 + k0);
                #pragma unroll
                for (int rt = 0; rt < 2; rt++) pacc[rt][ct] = MFMA16(afr[rt], bfr, pacc[rt][ct]);
            }
        }
    }
    {   // txt_out contribution: (selt * encT) @ W_tp
        _Float16 s[2];
        #pragma unroll
        for (int rt = 0; rt < 2; rt++) s[rt] = (_Float16)selt[rt*16 + l16];
        for (int ks = 0; ks < 8; ks++) {
            const int k0 = ks*32 + q4*8;
            half8 afr[2];
            #pragma unroll
            for (int rt = 0; rt < 2; rt++)
                afr[rt] = (*(const half8*)(encT + (rt*16+l16)*264 + k0)) * splat8(s[rt]);
            #pragma unroll
            for (int ct = 0; ct < 8; ct++) {
                const int ng = w*128 + ct*16 + l16;
                half8 bfr = *(const half8*)(g_WtpT + (size_t)ng*256 + k0);
                #pragma unroll
                for (int rt = 0; rt < 2; rt++) pacc[rt][ct] = MFMA16(afr[rt], bfr, pacc[rt][ct]);
            }
        }
    }

    // ---------------- stage 4: attention pooling into registers ----------------
    floatx4 poolacc[4][2];
    #pragma unroll
    for (int h = 0; h < 4; h++)
        #pragma unroll
        for (int rt = 0; rt < 2; rt++) poolacc[h][rt] = (floatx4){0.f,0.f,0.f,0.f};

    #pragma unroll
    for (int h = 0; h < 4; h++) {
        _Float16 a0l[2], a1l[2];
        #pragma unroll
        for (int rt = 0; rt < 2; rt++) {
            const int rr = rt*16 + l16;
            a0l[rt] = (_Float16)attn[(rr*4+h)*2];
            a1l[rt] = (_Float16)attn[(rr*4+h)*2+1];
        }
        const int ng = h*64 + w*16 + l16;
        for (int ks = 0; ks < 8; ks++) {
            const int k0 = ks*32 + q4*8;
            half8 bfr = *(const half8*)(g_WvT + (size_t)ng*256 + k0);
            #pragma unroll
            for (int rt = 0; rt < 2; rt++) {
                half8 eI = *(const half8*)(encI + (rt*16+l16)*264 + k0);
                half8 eT = *(const half8*)(encT + (rt*16+l16)*264 + k0);
                half8 m  = eI * splat8(a0l[rt]) + eT * splat8(a1l[rt]);
                poolacc[h][rt] = MFMA16(m, bfr, poolacc[h][rt]);
            }
        }
    }
    __syncthreads();   // B3: ALL reads of encI/encT done -> pool may overlay encT

    // write pool (selb folded in; bias bv folded in)
    #pragma unroll
    for (int h = 0; h < 4; h++) {
        const int colg = h*64 + w*16 + l16;
        const float bvv = bv[colg];
        #pragma unroll
        for (int rt = 0; rt < 2; rt++)
            #pragma unroll
            for (int r = 0; r < 4; r++) {
                const int row = rt*16 + q4*4 + r;
                pool[row*264 + colg] = (_Float16)((poolacc[h][rt][r] + bvv) * selb[row]);
            }
    }
    __syncthreads();   // B4: pool visible

    {   // fusion contribution: pool @ Wof (selb already folded into pool)
        for (int ks = 0; ks < 8; ks++) {
            const int k0 = ks*32 + q4*8;
            half8 afr[2];
            #pragma unroll
            for (int rt = 0; rt < 2; rt++)
                afr[rt] = *(const half8*)(pool + (rt*16+l16)*264 + k0);
            #pragma unroll
            for (int ct = 0; ct < 8; ct++) {
                const int ng = w*128 + ct*16 + l16;
                half8 bfr = *(const half8*)(g_WofT + (size_t)ng*256 + k0);
                #pragma unroll
                for (int rt = 0; rt < 2; rt++) pacc[rt][ct] = MFMA16(afr[rt], bfr, pacc[rt][ct]);
            }
        }
    }
    __syncthreads();   // B5: pool reads done; fused overlays encI+pool

    // fused = pacc + branch bias -> fp16 LDS
    {
        float sB[8], sI2[8], sT2[8];
        #pragma unroll
        for (int rt = 0; rt < 2; rt++)
            #pragma unroll
            for (int r = 0; r < 4; r++) {
                const int row = rt*16 + q4*4 + r;
                sB[rt*4+r] = selb[row]; sI2[rt*4+r] = seli[row]; sT2[rt*4+r] = selt[row];
            }
        #pragma unroll
        for (int ct = 0; ct < 8; ct++) {
            const int colg = w*128 + ct*16 + l16;
            const float bof = g_biasof[colg], bip = b_ip[colg], btp = b_tp[colg];
            #pragma unroll
            for (int rt = 0; rt < 2; rt++)
                #pragma unroll
                for (int r = 0; r < 4; r++) {
                    const int row = rt*16 + q4*4 + r;
                    const float f = pacc[rt][ct][r] + sB[rt*4+r]*bof + sI2[rt*4+r]*bip + sT2[rt*4+r]*btp;
                    fused[row*520 + colg] = (_Float16)f;
                }
        }
    }
    __syncthreads();   // B6: fused visible

    // ---------------- stage 5: classifier layer 1 ----------------
    {
        floatx4 cacc[2][4];
        #pragma unroll
        for (int rt = 0; rt < 2; rt++)
            #pragma unroll
            for (int ct = 0; ct < 4; ct++) cacc[rt][ct] = (floatx4){0.f,0.f,0.f,0.f};
        for (int ks = 0; ks < 16; ks++) {
            const int k0 = ks*32 + q4*8;
            half8 afr[2];
            #pragma unroll
            for (int rt = 0; rt < 2; rt++)
                afr[rt] = *(const half8*)(fused + (rt*16+l16)*520 + k0);
            #pragma unroll
            for (int ct = 0; ct < 4; ct++) {
                const int ng = w*64 + ct*16 + l16;
                half8 bfr = *(const half8*)(g_Wc1T + (size_t)ng*512 + k0);
                #pragma unroll
                for (int rt = 0; rt < 2; rt++) cacc[rt][ct] = MFMA16(afr[rt], bfr, cacc[rt][ct]);
            }
        }
        __syncthreads();   // B6a: fused reads done; h1 overlays fused low half
        #pragma unroll
        for (int ct = 0; ct < 4; ct++) {
            const int colg = w*64 + ct*16 + l16;
            const float b1 = bc1[colg];
            #pragma unroll
            for (int rt = 0; rt < 2; rt++)
                #pragma unroll
                for (int r = 0; r < 4; r++) {
                    float v = cacc[rt][ct][r] + b1;
                    v = v > 0.f ? v : 0.f;                         // relu
                    h1[(rt*16 + q4*4 + r)*264 + colg] = (_Float16)v;
                }
        }
    }
    __syncthreads();   // B7: h1 visible

    // ---------------- stage 6: classifier layer 2 + store ----------------
    for (int p = w; p < 10; p += 4) {          // 10 (rt,ct) tile pairs over [32][80]
        const int rt = p / 5, ct = p % 5;
        const int ng = ct*16 + l16;
        floatx4 a2 = (floatx4){0.f,0.f,0.f,0.f};
        for (int ks = 0; ks < 8; ks++) {
            const int k0 = ks*32 + q4*8;
            half8 afr = *(const half8*)(h1 + (rt*16+l16)*264 + k0);
            half8 bfr = *(const half8*)(g_Wc2T + (size_t)ng*256 + k0);
            a2 = MFMA16(afr, bfr, a2);
        }
        const float b2 = bc2[ng];
        #pragma unroll
        for (int r = 0; r < 4; r++) {
            const int rowg = base + rt*16 + q4*4 + r;
            out[(size_t)rowg*NC + ng] = a2[r] + b2;
        }
    }
}

// ============================ launch ============================
extern "C" void kernel_launch(void* const* d_in, const int* in_sizes, int n_in,
                              void* d_out, int out_size, void* d_ws, size_t ws_size,
                              hipStream_t stream)
{
    const float* img  = (const float*)d_in[0];
    const float* txt  = (const float*)d_in[1];
    const float* W_ie = (const float*)d_in[2];
    const float* b_ie = (const float*)d_in[3];
    const float* W_te = (const float*)d_in[4];
    const float* b_te = (const float*)d_in[5];
    const float* fq   = (const float*)d_in[6];
    const float* Wq   = (const float*)d_in[7];
    const float* bq   = (const float*)d_in[8];
    const float* Wk   = (const float*)d_in[9];
    const float* bk   = (const float*)d_in[10];
    const float* Wv   = (const float*)d_in[11];
    const float* bv   = (const float*)d_in[12];
    const float* Wo   = (const float*)d_in[13];
    const float* bo   = (const float*)d_in[14];
    const float* W_ip = (const float*)d_in[15];
    const float* b_ip = (const float*)d_in[16];
    const float* W_tp = (const float*)d_in[17];
    const float* b_tp = (const float*)d_in[18];
    const float* W_fp = (const float*)d_in[19];
    const float* b_fp = (const float*)d_in[20];
    const float* Wc1  = (const float*)d_in[21];
    const float* bc1  = (const float*)d_in[22];
    const float* Wc2  = (const float*)d_in[23];
    const float* bc2  = (const float*)d_in[24];
    float* out = (float*)d_out;

    hipFuncSetAttribute((const void*)aecf_main,
                        hipFuncAttributeMaxDynamicSharedMemorySize, SMEM_BYTES);

    aecf_setup<<<3411, 256, 0, stream>>>(W_ie, W_te, fq, Wq, bq, Wk, bk, Wv,
                                         Wo, bo, W_ip, W_tp, W_fp, b_fp, Wc1, Wc2);
    aecf_main<<<NBLK, 256, SMEM_BYTES, stream>>>(img, txt, b_ie, b_te, bv,
                                                 b_ip, b_tp, bc1, bc2, out);
}

// Round 4
// 1568.033 us; speedup vs baseline: 1.2753x; 1.2753x over previous
//
#include <hip/hip_runtime.h>
#include <hip/hip_fp16.h>
#include <math.h>

// ---------------- problem constants ----------------
constexpr int H   = 256;
constexpr int ID  = 512;   // image_dim == text_dim
constexpr int NC  = 80;
constexpr int BT  = 131072;

constexpr int MROWS = 32;              // rows per block (2 row-tiles of 16)
constexpr int NBLK  = BT / MROWS;      // 4096, exact -> no tail predication

typedef _Float16 half8  __attribute__((ext_vector_type(8)));
typedef float    floatx4 __attribute__((ext_vector_type(4)));

#define MFMA16(a,b,c) __builtin_amdgcn_mfma_f32_16x16x32_f16((a),(b),(c),0,0,0)

__device__ inline half8 splat8(_Float16 v){ half8 r = {v,v,v,v,v,v,v,v}; return r; }

// ---------------- device-global fp16 weights (transposed [N][K]) ----------------
__device__ __align__(16) _Float16 g_WieT[H*ID];     // [256][512]
__device__ __align__(16) _Float16 g_WteT[H*ID];     // [256][512]
__device__ __align__(16) _Float16 g_WvT [H*H];      // [256][256]
__device__ __align__(16) _Float16 g_AT  [H*H];      // [256][256] = (W_ip@Wc1)^T
__device__ __align__(16) _Float16 g_BT  [H*H];      // [256][256] = (W_tp@Wc1)^T
__device__ __align__(16) _Float16 g_CT  [H*H];      // [256][256] = (Wo@W_fp@Wc1)^T
__device__ __align__(16) _Float16 g_Wc2T[NC*H];     // [80][256]
__device__ __align__(16) float g_E[H*H];            // [256][256] = W_fp@Wc1 (f32 temp)
__device__ __align__(16) float g_wkeff[4*H];        // [4][256]  Wk folded with q, /8 (h-major)
__device__ float g_sbias[4];                        // bk folded with q, /8
__device__ float g_dI[H];                           // b_ip@Wc1
__device__ float g_dT[H];                           // b_tp@Wc1
__device__ float g_dF[H];                           // (bo@W_fp + b_fp)@Wc1

// ---------------- LDS layout (dynamic) ----------------
// half-unit offsets:
//   encI  [32][264] @ 0      -> h1 overlays after all enc reads done
//   encT  [32][264] @ 8448   -> pool overlays after B3
constexpr int OFF_EI = 0;
constexpr int OFF_ET = 8448;      // half units
// byte offsets for f32 scalar regions:
constexpr int OFF_SUMI = 33792;   // f32[32][4]
constexpr int OFF_SUMT = 34304;   // f32[32][4]
constexpr int OFF_ATT  = 34816;   // f32[32][4][2]
constexpr int OFF_SELB = 35840;   // f32[32]
constexpr int OFF_SELI = 35968;
constexpr int OFF_SELT = 36096;
constexpr int SMEM_BYTES = 36224; // 36.2KB -> 4 blocks/CU (144896 <= 163840)

// ============================ setup kernel 1 ============================
// [0,88)   transposed fp16 conversions (64x64 tiles via LDS)
// [88,104) E = W_fp@Wc1  (f32)
// [104,136) AT/BT = (W_ip@Wc1)^T / (W_tp@Wc1)^T fp16
// 136      dI/dT/dF-partial vectors
// 137      wkeff + sbias
__global__ void aecf_setup1(const float* __restrict__ W_ie, const float* __restrict__ W_te,
                            const float* __restrict__ Wv,   const float* __restrict__ Wc2,
                            const float* __restrict__ W_ip, const float* __restrict__ W_tp,
                            const float* __restrict__ W_fp, const float* __restrict__ Wc1,
                            const float* __restrict__ b_ip, const float* __restrict__ b_tp,
                            const float* __restrict__ b_fp, const float* __restrict__ fq,
                            const float* __restrict__ Wq,   const float* __restrict__ bq,
                            const float* __restrict__ Wk,   const float* __restrict__ bk)
{
    __shared__ float tile[64][69];   // padded (odd stride -> 2-way max on transposed read)
    __shared__ float qv[256];
    int b = blockIdx.x;
    const int t = threadIdx.x;

    if (b < 88) {   // ---- transpose+convert: src[K][N] f32 -> dst[N][K] fp16 ----
        const float* src; _Float16* dst; int K, N, ti;
        if (b < 32)      { src = W_ie; dst = g_WieT; K = 512; N = 256; ti = b;      }
        else if (b < 64) { src = W_te; dst = g_WteT; K = 512; N = 256; ti = b - 32; }
        else if (b < 80) { src = Wv;   dst = g_WvT;  K = 256; N = 256; ti = b - 64; }
        else             { src = Wc2;  dst = g_Wc2T; K = 256; N = 80;  ti = b - 80; }
        const int ntn = (N + 63) >> 6;
        const int k0 = (ti / ntn) * 64, n0 = (ti % ntn) * 64;
        #pragma unroll
        for (int p = 0; p < 4; p++) {
            const int r = (t >> 4) + p * 16;
            const int c = (t & 15) * 4;
            floatx4 v = {0.f, 0.f, 0.f, 0.f};
            if (n0 + c + 4 <= N) v = *(const floatx4*)(src + (size_t)(k0 + r) * N + n0 + c);
            tile[r][c] = v[0]; tile[r][c+1] = v[1]; tile[r][c+2] = v[2]; tile[r][c+3] = v[3];
        }
        __syncthreads();
        const int n = n0 + (t >> 2);
        if (n < N) {
            const int kl = (t & 3) * 16;
            half8 h0, h1v;
            #pragma unroll
            for (int j = 0; j < 8; j++) { h0[j]  = (_Float16)tile[kl + j][t >> 2];
                                          h1v[j] = (_Float16)tile[kl + 8 + j][t >> 2]; }
            *(half8*)(dst + (size_t)n * K + k0 + kl)     = h0;
            *(half8*)(dst + (size_t)n * K + k0 + kl + 8) = h1v;
        }
        return;
    }
    b -= 88;
    if (b < 16) {   // ---- E = W_fp@Wc1, f32, straight store ----
        const int p  = (b >> 2) * 64 + (t >> 2);
        const int nb = (b & 3) * 64 + (t & 3) * 16;
        floatx4 a0 = {0,0,0,0}, a1 = a0, a2 = a0, a3 = a0;
        for (int m = 0; m < 512; m++) {
            const float wf = W_fp[(size_t)p * 512 + m];
            const float* wr = Wc1 + (size_t)m * 256 + nb;
            a0 += wf * *(const floatx4*)wr;       a1 += wf * *(const floatx4*)(wr + 4);
            a2 += wf * *(const floatx4*)(wr + 8); a3 += wf * *(const floatx4*)(wr + 12);
        }
        float* er = g_E + (size_t)p * 256 + nb;
        *(floatx4*)er = a0; *(floatx4*)(er+4) = a1; *(floatx4*)(er+8) = a2; *(floatx4*)(er+12) = a3;
        return;
    }
    b -= 16;
    if (b < 32) {   // ---- AT/BT = (W@Wc1)^T fp16 via LDS transpose ----
        const float* W = (b < 16) ? W_ip : W_tp;
        _Float16* dst  = (b < 16) ? g_AT : g_BT;
        const int a = b & 15;
        const int k0 = (a >> 2) * 64, n0 = (a & 3) * 64;
        const int k  = k0 + (t >> 2);
        const int nb = n0 + (t & 3) * 16;
        floatx4 a0 = {0,0,0,0}, a1 = a0, a2 = a0, a3 = a0;
        for (int m = 0; m < 512; m++) {
            const float wv = W[(size_t)k * 512 + m];
            const float* wr = Wc1 + (size_t)m * 256 + nb;
            a0 += wv * *(const floatx4*)wr;       a1 += wv * *(const floatx4*)(wr + 4);
            a2 += wv * *(const floatx4*)(wr + 8); a3 += wv * *(const floatx4*)(wr + 12);
        }
        const int kl = t >> 2, nl = (t & 3) * 16;
        #pragma unroll
        for (int j = 0; j < 4; j++) { tile[kl][nl+j] = a0[j]; tile[kl][nl+4+j] = a1[j];
                                      tile[kl][nl+8+j] = a2[j]; tile[kl][nl+12+j] = a3[j]; }
        __syncthreads();
        const int n = n0 + (t >> 2);
        const int kl2 = (t & 3) * 16;
        half8 h0, h1v;
        #pragma unroll
        for (int j = 0; j < 8; j++) { h0[j]  = (_Float16)tile[kl2 + j][t >> 2];
                                      h1v[j] = (_Float16)tile[kl2 + 8 + j][t >> 2]; }
        *(half8*)(dst + (size_t)n * 256 + k0 + kl2)     = h0;
        *(half8*)(dst + (size_t)n * 256 + k0 + kl2 + 8) = h1v;
        return;
    }
    b -= 32;
    if (b == 0) {   // ---- dI/dT/dF-partial ----
        float di = 0.f, dt = 0.f, df = 0.f;
        for (int m = 0; m < 512; m++) {
            const float wc = Wc1[(size_t)m * 256 + t];
            di += b_ip[m] * wc; dt += b_tp[m] * wc; df += b_fp[m] * wc;
        }
        g_dI[t] = di; g_dT[t] = dt; g_dF[t] = df;   // dF gets +bo@E in setup2
        return;
    }
    {   // ---- wkeff + sbias ----
        float a = bq[t];
        for (int i = 0; i < 256; i++) a += fq[i] * Wq[i*256+t];
        qv[t] = a;
        __syncthreads();
        for (int h = 0; h < 4; h++) {
            float s = 0.f;
            for (int d = 0; d < 64; d++) s += Wk[t*256 + h*64+d] * qv[h*64+d];
            g_wkeff[h*256 + t] = s * 0.125f;
        }
        if (t < 4) {
            float s = 0.f;
            for (int d = 0; d < 64; d++) s += bk[t*64+d] * qv[t*64+d];
            g_sbias[t] = s * 0.125f;
        }
    }
}

// ============================ setup kernel 2 (needs E) ============================
// [0,16) CT = (Wo@E)^T fp16 | 16: dF += bo@E
__global__ void aecf_setup2(const float* __restrict__ Wo, const float* __restrict__ bo)
{
    __shared__ float tile[64][69];
    const int b = blockIdx.x, t = threadIdx.x;
    if (b < 16) {
        const int k0 = (b >> 2) * 64, n0 = (b & 3) * 64;
        const int k  = k0 + (t >> 2);
        const int nb = n0 + (t & 3) * 16;
        floatx4 a0 = {0,0,0,0}, a1 = a0, a2 = a0, a3 = a0;
        for (int p = 0; p < 256; p++) {
            const float wv = Wo[(size_t)k * 256 + p];
            const float* er = g_E + (size_t)p * 256 + nb;
            a0 += wv * *(const floatx4*)er;       a1 += wv * *(const floatx4*)(er + 4);
            a2 += wv * *(const floatx4*)(er + 8); a3 += wv * *(const floatx4*)(er + 12);
        }
        const int kl = t >> 2, nl = (t & 3) * 16;
        #pragma unroll
        for (int j = 0; j < 4; j++) { tile[kl][nl+j] = a0[j]; tile[kl][nl+4+j] = a1[j];
                                      tile[kl][nl+8+j] = a2[j]; tile[kl][nl+12+j] = a3[j]; }
        __syncthreads();
        const int n = n0 + (t >> 2);
        const int kl2 = (t & 3) * 16;
        half8 h0, h1v;
        #pragma unroll
        for (int j = 0; j < 8; j++) { h0[j]  = (_Float16)tile[kl2 + j][t >> 2];
                                      h1v[j] = (_Float16)tile[kl2 + 8 + j][t >> 2]; }
        *(half8*)(g_CT + (size_t)n * 256 + k0 + kl2)     = h0;
        *(half8*)(g_CT + (size_t)n * 256 + k0 + kl2 + 8) = h1v;
        return;
    }
    {
        float s = g_dF[t];
        for (int p = 0; p < 256; p++) s += bo[p] * g_E[(size_t)p * 256 + t];
        g_dF[t] = s;
    }
}

// ============================ main fused kernel ============================
__global__ __launch_bounds__(256, 4)
void aecf_main(const float* __restrict__ img, const float* __restrict__ txt,
               const float* __restrict__ b_ie, const float* __restrict__ b_te,
               const float* __restrict__ bv,   const float* __restrict__ bc1,
               const float* __restrict__ bc2,  float* __restrict__ out)
{
    extern __shared__ char smem[];
    _Float16* encI  = (_Float16*)smem + OFF_EI;   // [32][264]
    _Float16* encT  = (_Float16*)smem + OFF_ET;   // [32][264]
    _Float16* pool  = (_Float16*)smem + OFF_ET;   // overlays encT after B3
    _Float16* h1    = (_Float16*)smem + OFF_EI;   // overlays encI after B4
    float* sumI = (float*)(smem + OFF_SUMI);
    float* sumT = (float*)(smem + OFF_SUMT);
    float* attn = (float*)(smem + OFF_ATT);
    float* selb = (float*)(smem + OFF_SELB);
    float* seli = (float*)(smem + OFF_SELI);
    float* selt = (float*)(smem + OFF_SELT);

    const int tid  = threadIdx.x;
    const int w    = tid >> 6;      // wave 0..3
    const int lane = tid & 63;
    const int l16  = lane & 15;
    const int q4   = lane >> 4;
    const int base = blockIdx.x * MROWS;

    // ---------------- stage 1: encoders, register-double-buffered input prefetch ----------------
    auto encode = [&](const float* __restrict__ src, const _Float16* __restrict__ WT,
                      const float* __restrict__ bias, _Float16* dstE, float* sumLds) {
        floatx4 acc[2][4];
        #pragma unroll
        for (int rt = 0; rt < 2; rt++)
            #pragma unroll
            for (int ct = 0; ct < 4; ct++) acc[rt][ct] = (floatx4){0.f,0.f,0.f,0.f};
        float sab[2] = {0.f, 0.f};

        const float* p0 = src + (size_t)(base + l16)*ID + q4*8;
        const float* p1 = src + (size_t)(base + 16 + l16)*ID + q4*8;
        floatx4 n00 = *(const floatx4*)p0, n01 = *(const floatx4*)(p0+4);
        floatx4 n10 = *(const floatx4*)p1, n11 = *(const floatx4*)(p1+4);

        for (int ks = 0; ks < 16; ks++) {
            const int k0 = ks*32 + q4*8;
            half8 afr[2];
            {
                half8 a;
                a[0]=(_Float16)n00[0]; a[1]=(_Float16)n00[1]; a[2]=(_Float16)n00[2]; a[3]=(_Float16)n00[3];
                a[4]=(_Float16)n01[0]; a[5]=(_Float16)n01[1]; a[6]=(_Float16)n01[2]; a[7]=(_Float16)n01[3];
                afr[0] = a;
                half8 c;
                c[0]=(_Float16)n10[0]; c[1]=(_Float16)n10[1]; c[2]=(_Float16)n10[2]; c[3]=(_Float16)n10[3];
                c[4]=(_Float16)n11[0]; c[5]=(_Float16)n11[1]; c[6]=(_Float16)n11[2]; c[7]=(_Float16)n11[3];
                afr[1] = c;
            }
            if (w == 0) {  // presence detection partials
                sab[0] += fabsf(n00[0])+fabsf(n00[1])+fabsf(n00[2])+fabsf(n00[3])
                        + fabsf(n01[0])+fabsf(n01[1])+fabsf(n01[2])+fabsf(n01[3]);
                sab[1] += fabsf(n10[0])+fabsf(n10[1])+fabsf(n10[2])+fabsf(n10[3])
                        + fabsf(n11[0])+fabsf(n11[1])+fabsf(n11[2])+fabsf(n11[3]);
            }
            if (ks < 15) {   // prefetch next k-slice (hides HBM under weights+MFMA)
                const int kn = (ks+1)*32;
                n00 = *(const floatx4*)(p0 + kn);  n01 = *(const floatx4*)(p0 + kn + 4);
                n10 = *(const floatx4*)(p1 + kn);  n11 = *(const floatx4*)(p1 + kn + 4);
            }
            #pragma unroll
            for (int ct = 0; ct < 4; ct++) {
                const int ng = w*64 + ct*16 + l16;
                half8 bfr = *(const half8*)(WT + (size_t)ng*512 + k0);
                #pragma unroll
                for (int rt = 0; rt < 2; rt++) acc[rt][ct] = MFMA16(afr[rt], bfr, acc[rt][ct]);
            }
        }
        #pragma unroll
        for (int ct = 0; ct < 4; ct++) {
            const int colg = w*64 + ct*16 + l16;
            const float bb = bias[colg];
            #pragma unroll
            for (int rt = 0; rt < 2; rt++)
                #pragma unroll
                for (int r = 0; r < 4; r++) {
                    float v = acc[rt][ct][r] + bb;
                    v = v > 0.f ? v : 0.f;                     // relu
                    dstE[(rt*16 + q4*4 + r)*264 + colg] = (_Float16)v;
                }
        }
        if (w == 0) {
            #pragma unroll
            for (int rt = 0; rt < 2; rt++) sumLds[(rt*16 + l16)*4 + q4] = sab[rt];
        }
    };
    encode(img, g_WieT, b_ie, encI, sumI);
    encode(txt, g_WteT, b_te, encT, sumT);
    __syncthreads();   // B1

    // ---------------- stage 2: flags + scores + softmax (vectorized) ----------------
    if (tid < 128) {
        const int row = tid >> 2, h = tid & 3;
        float sI = sumI[row*4]+sumI[row*4+1]+sumI[row*4+2]+sumI[row*4+3];
        float sT = sumT[row*4]+sumT[row*4+1]+sumT[row*4+2]+sumT[row*4+3];
        bool pi = sI > 0.f, pt = sT > 0.f;
        if (h == 0) {
            selb[row] = (pi && pt)  ? 1.f : 0.f;
            seli[row] = (pi && !pt) ? 1.f : 0.f;
            selt[row] = (!pi && pt) ? 1.f : 0.f;
        }
        float s0 = g_sbias[h], s1 = s0;
        const _Float16* rI = encI + row*264;
        const _Float16* rT = encT + row*264;
        const float* wkh = g_wkeff + h*256;
        for (int c8 = 0; c8 < 256; c8 += 8) {
            half8 eI = *(const half8*)(rI + c8);
            half8 eT = *(const half8*)(rT + c8);
            floatx4 wa = *(const floatx4*)(wkh + c8);
            floatx4 wb = *(const floatx4*)(wkh + c8 + 4);
            s0 += wa[0]*(float)eI[0] + wa[1]*(float)eI[1] + wa[2]*(float)eI[2] + wa[3]*(float)eI[3]
                + wb[0]*(float)eI[4] + wb[1]*(float)eI[5] + wb[2]*(float)eI[6] + wb[3]*(float)eI[7];
            s1 += wa[0]*(float)eT[0] + wa[1]*(float)eT[1] + wa[2]*(float)eT[2] + wa[3]*(float)eT[3]
                + wb[0]*(float)eT[4] + wb[1]*(float)eT[5] + wb[2]*(float)eT[6] + wb[3]*(float)eT[7];
        }
        const float a0 = 1.f / (1.f + __expf(s1 - s0));
        attn[(row*4+h)*2]   = a0;
        attn[(row*4+h)*2+1] = 1.f - a0;
    }
    __syncthreads();   // B2

    // ---------------- stage 3: pool (regs) + h1-accumulation over folded weights ----------------
    floatx4 poolacc[4][2];
    #pragma unroll
    for (int h = 0; h < 4; h++)
        #pragma unroll
        for (int rt = 0; rt < 2; rt++) poolacc[h][rt] = (floatx4){0.f,0.f,0.f,0.f};

    #pragma unroll
    for (int h = 0; h < 4; h++) {
        _Float16 a0l[2], a1l[2];
        #pragma unroll
        for (int rt = 0; rt < 2; rt++) {
            const int rr = rt*16 + l16;
            a0l[rt] = (_Float16)attn[(rr*4+h)*2];
            a1l[rt] = (_Float16)attn[(rr*4+h)*2+1];
        }
        const int ng = h*64 + w*16 + l16;
        for (int ks = 0; ks < 8; ks++) {
            const int k0 = ks*32 + q4*8;
            half8 bfr = *(const half8*)(g_WvT + (size_t)ng*256 + k0);
            #pragma unroll
            for (int rt = 0; rt < 2; rt++) {
                half8 eI = *(const half8*)(encI + (rt*16+l16)*264 + k0);
                half8 eT = *(const half8*)(encT + (rt*16+l16)*264 + k0);
                half8 m  = eI * splat8(a0l[rt]) + eT * splat8(a1l[rt]);
                poolacc[h][rt] = MFMA16(m, bfr, poolacc[h][rt]);
            }
        }
    }

    // hacc = (seli*encI)@A + (selt*encT)@B  (+ pool@C after B4) -- 256-wide only!
    floatx4 hacc[2][4];
    #pragma unroll
    for (int rt = 0; rt < 2; rt++)
        #pragma unroll
        for (int ct = 0; ct < 4; ct++) hacc[rt][ct] = (floatx4){0.f,0.f,0.f,0.f};

    {   // img branch through folded A = W_ip@Wc1
        _Float16 s[2];
        #pragma unroll
        for (int rt = 0; rt < 2; rt++) s[rt] = (_Float16)seli[rt*16 + l16];
        for (int ks = 0; ks < 8; ks++) {
            const int k0 = ks*32 + q4*8;
            half8 afr[2];
            #pragma unroll
            for (int rt = 0; rt < 2; rt++)
                afr[rt] = (*(const half8*)(encI + (rt*16+l16)*264 + k0)) * splat8(s[rt]);
            #pragma unroll
            for (int ct = 0; ct < 4; ct++) {
                const int ng = w*64 + ct*16 + l16;
                half8 bfr = *(const half8*)(g_AT + (size_t)ng*256 + k0);
                #pragma unroll
                for (int rt = 0; rt < 2; rt++) hacc[rt][ct] = MFMA16(afr[rt], bfr, hacc[rt][ct]);
            }
        }
    }
    {   // txt branch through folded B = W_tp@Wc1
        _Float16 s[2];
        #pragma unroll
        for (int rt = 0; rt < 2; rt++) s[rt] = (_Float16)selt[rt*16 + l16];
        for (int ks = 0; ks < 8; ks++) {
            const int k0 = ks*32 + q4*8;
            half8 afr[2];
            #pragma unroll
            for (int rt = 0; rt < 2; rt++)
                afr[rt] = (*(const half8*)(encT + (rt*16+l16)*264 + k0)) * splat8(s[rt]);
            #pragma unroll
            for (int ct = 0; ct < 4; ct++) {
                const int ng = w*64 + ct*16 + l16;
                half8 bfr = *(const half8*)(g_BT + (size_t)ng*256 + k0);
                #pragma unroll
                for (int rt = 0; rt < 2; rt++) hacc[rt][ct] = MFMA16(afr[rt], bfr, hacc[rt][ct]);
            }
        }
    }
    __syncthreads();   // B3: ALL enc reads done -> pool overlays encT

    // write pool (bv + selb folded in); poolacc dies here
    #pragma unroll
    for (int h = 0; h < 4; h++) {
        const int colg = h*64 + w*16 + l16;
        const float bvv = bv[colg];
        #pragma unroll
        for (int rt = 0; rt < 2; rt++)
            #pragma unroll
            for (int r = 0; r < 4; r++) {
                const int row = rt*16 + q4*4 + r;
                pool[row*264 + colg] = (_Float16)((poolacc[h][rt][r] + bvv) * selb[row]);
            }
    }
    __syncthreads();   // B4: pool visible

    {   // fusion branch through folded C = Wo@W_fp@Wc1 (selb already in pool)
        for (int ks = 0; ks < 8; ks++) {
            const int k0 = ks*32 + q4*8;
            half8 afr[2];
            #pragma unroll
            for (int rt = 0; rt < 2; rt++)
                afr[rt] = *(const half8*)(pool + (rt*16+l16)*264 + k0);
            #pragma unroll
            for (int ct = 0; ct < 4; ct++) {
                const int ng = w*64 + ct*16 + l16;
                half8 bfr = *(const half8*)(g_CT + (size_t)ng*256 + k0);
                #pragma unroll
                for (int rt = 0; rt < 2; rt++) hacc[rt][ct] = MFMA16(afr[rt], bfr, hacc[rt][ct]);
            }
        }
    }

    // h1 = relu(hacc + bc1 + sel-weighted folded biases) -> overlays encI
    {
        float sB[8], sI2[8], sT2[8];
        #pragma unroll
        for (int rt = 0; rt < 2; rt++)
            #pragma unroll
            for (int r = 0; r < 4; r++) {
                const int row = rt*16 + q4*4 + r;
                sB[rt*4+r] = selb[row]; sI2[rt*4+r] = seli[row]; sT2[rt*4+r] = selt[row];
            }
        #pragma unroll
        for (int ct = 0; ct < 4; ct++) {
            const int colg = w*64 + ct*16 + l16;
            const float b1 = bc1[colg];
            const float di = g_dI[colg], dt = g_dT[colg], df = g_dF[colg];
            #pragma unroll
            for (int rt = 0; rt < 2; rt++)
                #pragma unroll
                for (int r = 0; r < 4; r++) {
                    const int row = rt*16 + q4*4 + r;
                    float v = hacc[rt][ct][r] + b1
                            + sB[rt*4+r]*df + sI2[rt*4+r]*di + sT2[rt*4+r]*dt;
                    v = v > 0.f ? v : 0.f;                     // relu
                    h1[row*264 + colg] = (_Float16)v;
                }
        }
    }
    __syncthreads();   // B5: h1 visible

    // ---------------- stage 7: classifier layer 2 + store ----------------
    for (int p = w; p < 10; p += 4) {          // 10 (rt,ct) tile pairs over [32][80]
        const int rt = p / 5, ct = p % 5;
        const int ng = ct*16 + l16;
        floatx4 a2 = (floatx4){0.f,0.f,0.f,0.f};
        for (int ks = 0; ks < 8; ks++) {
            const int k0 = ks*32 + q4*8;
            half8 afr = *(const half8*)(h1 + (rt*16+l16)*264 + k0);
            half8 bfr = *(const half8*)(g_Wc2T + (size_t)ng*256 + k0);
            a2 = MFMA16(afr, bfr, a2);
        }
        const float b2 = bc2[ng];
        #pragma unroll
        for (int r = 0; r < 4; r++) {
            const int rowg = base + rt*16 + q4*4 + r;
            out[(size_t)rowg*NC + ng] = a2[r] + b2;
        }
    }
}

// ============================ launch ============================
extern "C" void kernel_launch(void* const* d_in, const int* in_sizes, int n_in,
                              void* d_out, int out_size, void* d_ws, size_t ws_size,
                              hipStream_t stream)
{
    const float* img  = (const float*)d_in[0];
    const float* txt  = (const float*)d_in[1];
    const float* W_ie = (const float*)d_in[2];
    const float* b_ie = (const float*)d_in[3];
    const float* W_te = (const float*)d_in[4];
    const float* b_te = (const float*)d_in[5];
    const float* fq   = (const float*)d_in[6];
    const float* Wq   = (const float*)d_in[7];
    const float* bq   = (const float*)d_in[8];
    const float* Wk   = (const float*)d_in[9];
    const float* bk   = (const float*)d_in[10];
    const float* Wv   = (const float*)d_in[11];
    const float* bv   = (const float*)d_in[12];
    const float* Wo   = (const float*)d_in[13];
    const float* bo   = (const float*)d_in[14];
    const float* W_ip = (const float*)d_in[15];
    const float* b_ip = (const float*)d_in[16];
    const float* W_tp = (const float*)d_in[17];
    const float* b_tp = (const float*)d_in[18];
    const float* W_fp = (const float*)d_in[19];
    const float* b_fp = (const float*)d_in[20];
    const float* Wc1  = (const float*)d_in[21];
    const float* bc1  = (const float*)d_in[22];
    const float* Wc2  = (const float*)d_in[23];
    const float* bc2  = (const float*)d_in[24];
    float* out = (float*)d_out;

    hipFuncSetAttribute((const void*)aecf_main,
                        hipFuncAttributeMaxDynamicSharedMemorySize, SMEM_BYTES);

    aecf_setup1<<<138, 256, 0, stream>>>(W_ie, W_te, Wv, Wc2, W_ip, W_tp, W_fp, Wc1,
                                         b_ip, b_tp, b_fp, fq, Wq, bq, Wk, bk);
    aecf_setup2<<<17, 256, 0, stream>>>(Wo, bo);
    aecf_main<<<NBLK, 256, SMEM_BYTES, stream>>>(img, txt, b_ie, b_te, bv, bc1, bc2, out);
}